// Round 9
// baseline (520.156 us; speedup 1.0000x reference)
//
#include <hip/hip_runtime.h>
#include <hip/hip_bf16.h>
#include <stdint.h>

// MQA: B=2, S=2048, D=1024, H=16, DH=64. Inputs f32, OUTPUT f32.
// r9: attention = r6 structure, but UNFENCED (no asm lgkmcnt / sched_barrier)
// + double-buffered K-hi register prefetch (unroll-by-2, static buffers).
// Split-KV and merge removed (r8: waves were never the limit).

#define B_   2
#define S_   2048
#define D_   1024
#define H_   16
#define DH_  64
#define MTOT (B_ * S_)  // 4096

typedef short bf16x8 __attribute__((ext_vector_type(8)));
typedef float f32x4 __attribute__((ext_vector_type(4)));
typedef short short4v __attribute__((ext_vector_type(4)));

__device__ __forceinline__ short f2bf(float f) {  // RNE f32->bf16
  unsigned u = __float_as_uint(f);
  u += 0x7FFF + ((u >> 16) & 1);
  return (short)(u >> 16);
}
__device__ __forceinline__ float bf2f(short h) {
  return __uint_as_float(((unsigned)(unsigned short)h) << 16);
}
struct bfpair { short hi, lo; };
__device__ __forceinline__ bfpair split2(float x) {
  bfpair p;
  p.hi = f2bf(x);
  p.lo = f2bf(x - bf2f(p.hi));
  return p;
}

__device__ __forceinline__ void glds16(const void* g, void* l) {
  __builtin_amdgcn_global_load_lds((const __attribute__((address_space(1))) void*)g,
                                   (__attribute__((address_space(3))) void*)l, 16, 0, 0);
}

// ---------------- f32 -> bf16 convert, hi/lo split where needed ----------------
__global__ __launch_bounds__(256) void cvt_split(
    const float* __restrict__ q, const float* __restrict__ k, const float* __restrict__ v,
    const float* __restrict__ wq, const float* __restrict__ wk, const float* __restrict__ wv,
    const float* __restrict__ wo,
    short* qhi, short* qlo, short* khi, short* klo, short* vb,
    short* wqh, short* wql, short* wkh, short* wkl, short* wvb,
    short* woh, short* wol) {
  const int U0 = 1048576, U1 = 2097152, U2 = 3145728, U3 = 3407872,
            U4 = 3424256, U5 = 3440640, U6 = 3702784;
  for (int u = blockIdx.x * blockDim.x + threadIdx.x; u < U6; u += gridDim.x * blockDim.x) {
    const float* s; short* dh; short* dl; int r;
    if (u < U0)      { s = q;  dh = qhi; dl = qlo; r = u; }
    else if (u < U1) { s = k;  dh = khi; dl = klo; r = u - U0; }
    else if (u < U2) { s = v;  dh = vb;  dl = nullptr; r = u - U1; }
    else if (u < U3) { s = wq; dh = wqh; dl = wql; r = u - U2; }
    else if (u < U4) { s = wk; dh = wkh; dl = wkl; r = u - U3; }
    else if (u < U5) { s = wv; dh = wvb; dl = nullptr; r = u - U4; }
    else             { s = wo; dh = woh; dl = wol; r = u - U5; }
    float4 x = *(const float4*)(s + (size_t)r * 4);
    bfpair p0 = split2(x.x), p1 = split2(x.y), p2 = split2(x.z), p3 = split2(x.w);
    short4v yh, yl;
    yh.x = p0.hi; yh.y = p1.hi; yh.z = p2.hi; yh.w = p3.hi;
    yl.x = p0.lo; yl.y = p1.lo; yl.z = p2.lo; yl.w = p3.lo;
    *(short4v*)(dh + (size_t)r * 4) = yh;
    if (dl) *(short4v*)(dl + (size_t)r * 4) = yl;
  }
}

// ---------------- GEMM  C = (Ah+Al) * (Bh+Bl)^T, f32 acc ----------------
template <int NPROD, int MODE>
__global__ __launch_bounds__(256) void gemm3(
    const short* __restrict__ Ah, const short* __restrict__ Al,
    const short* __restrict__ Bh, const short* __restrict__ Bl,
    short* __restrict__ Ch, short* __restrict__ Cl, float* __restrict__ Cf,
    int K, int lda, int ldb, int ldc, float alpha) {
  __shared__ alignas(16) short Ash[4096], Asl[4096], Bsh[4096], Bsl[4096];
  const int tid = threadIdx.x;
  const int lane = tid & 63, w = tid >> 6;
  const int c = lane & 15, g = lane >> 4;
  const int wm = w >> 1, wn = w & 1;
  const int bm = blockIdx.x * 64, bn = blockIdx.y * 64;
  const int sr = lane >> 3;
  const int scs = ((lane & 7) ^ sr) * 8;

  f32x4 acc[2][2] = {};
  for (int k0 = 0; k0 < K; k0 += 64) {
    glds16(Ah + (size_t)(bm + w * 8 + sr) * lda + k0 + scs,      Ash + w * 512);
    glds16(Ah + (size_t)(bm + 32 + w * 8 + sr) * lda + k0 + scs, Ash + 2048 + w * 512);
    glds16(Bh + (size_t)(bn + w * 8 + sr) * ldb + k0 + scs,      Bsh + w * 512);
    glds16(Bh + (size_t)(bn + 32 + w * 8 + sr) * ldb + k0 + scs, Bsh + 2048 + w * 512);
    if constexpr (NPROD == 3) {
      glds16(Al + (size_t)(bm + w * 8 + sr) * lda + k0 + scs,      Asl + w * 512);
      glds16(Al + (size_t)(bm + 32 + w * 8 + sr) * lda + k0 + scs, Asl + 2048 + w * 512);
      glds16(Bl + (size_t)(bn + w * 8 + sr) * ldb + k0 + scs,      Bsl + w * 512);
      glds16(Bl + (size_t)(bn + 32 + w * 8 + sr) * ldb + k0 + scs, Bsl + 2048 + w * 512);
    }
    __syncthreads();
#pragma unroll
    for (int kk = 0; kk < 2; ++kk) {
      bf16x8 ah[2], bh[2], al[2], bl[2];
#pragma unroll
      for (int mt = 0; mt < 2; ++mt) {
        int row = wm * 32 + mt * 16 + c;
        int so = row * 64 + (((kk * 4 + g) ^ (row & 7)) * 8);
        ah[mt] = *(const bf16x8*)(Ash + so);
        if constexpr (NPROD == 3) al[mt] = *(const bf16x8*)(Asl + so);
      }
#pragma unroll
      for (int nt = 0; nt < 2; ++nt) {
        int row = wn * 32 + nt * 16 + c;
        int so = row * 64 + (((kk * 4 + g) ^ (row & 7)) * 8);
        bh[nt] = *(const bf16x8*)(Bsh + so);
        if constexpr (NPROD == 3) bl[nt] = *(const bf16x8*)(Bsl + so);
      }
#pragma unroll
      for (int mt = 0; mt < 2; ++mt)
#pragma unroll
        for (int nt = 0; nt < 2; ++nt) {
          acc[mt][nt] = __builtin_amdgcn_mfma_f32_16x16x32_bf16(ah[mt], bh[nt], acc[mt][nt], 0, 0, 0);
          if constexpr (NPROD == 3) {
            acc[mt][nt] = __builtin_amdgcn_mfma_f32_16x16x32_bf16(ah[mt], bl[nt], acc[mt][nt], 0, 0, 0);
            acc[mt][nt] = __builtin_amdgcn_mfma_f32_16x16x32_bf16(al[mt], bh[nt], acc[mt][nt], 0, 0, 0);
          }
        }
    }
    __syncthreads();
  }
#pragma unroll
  for (int mt = 0; mt < 2; ++mt) {
#pragma unroll
    for (int nt = 0; nt < 2; ++nt) {
      if constexpr (MODE == 0) {
#pragma unroll
        for (int r = 0; r < 4; ++r) {
          int m = bm + wm * 32 + mt * 16 + g * 4 + r;
          int n = bn + wn * 32 + nt * 16 + c;
          bfpair pr = split2(acc[mt][nt][r] * alpha);
          Ch[(size_t)m * ldc + n] = pr.hi;
          Cl[(size_t)m * ldc + n] = pr.lo;
        }
      } else if constexpr (MODE == 1) {
        int n = bn + wn * 32 + nt * 16 + c;
        int m = bm + wm * 32 + mt * 16 + g * 4;
        short4v y;
        y.x = f2bf(acc[mt][nt][0] * alpha);
        y.y = f2bf(acc[mt][nt][1] * alpha);
        y.z = f2bf(acc[mt][nt][2] * alpha);
        y.w = f2bf(acc[mt][nt][3] * alpha);
        *(short4v*)(Ch + (size_t)n * ldc + m) = y;
      } else {
#pragma unroll
        for (int r = 0; r < 4; ++r) {
          int m = bm + wm * 32 + mt * 16 + g * 4 + r;
          int n = bn + wn * 32 + nt * 16 + c;
          Cf[(size_t)m * ldc + n] = acc[mt][nt][r] * alpha;
        }
      }
    }
  }
}

// ---------------- flash MQA attention v3: unfenced + K-prefetch pipeline --------
// grid (S/64, H, B), 256 thr. Wave w: 16 q-rows, BKV=64, online softmax.
struct KHt { bf16x8 h[8]; };  // one kv-tile's K-hi fragments (4 nt x 2 halves)

__global__ __launch_bounds__(256, 4) void mqa_attn(
    const short* __restrict__ qph, const short* __restrict__ qpl,
    const short* __restrict__ kph, const short* __restrict__ kpl,
    const short* __restrict__ vt, short* __restrict__ aoh, short* __restrict__ aol) {
  __shared__ alignas(16) short Plds[4 * 16 * 64];
  const int tid = threadIdx.x;
  const int lane = tid & 63, w = tid >> 6;
  const int c = lane & 15, g = lane >> 4;
  const int qt = blockIdx.x, h = blockIdx.y, b = blockIdx.z;
  const int q0 = qt * 64 + w * 16;

  const size_t qrow = (size_t)(b * S_ + q0 + c) * D_ + h * DH_;
  bf16x8 aqh0 = *(const bf16x8*)(qph + qrow + g * 8);
  bf16x8 aqh1 = *(const bf16x8*)(qph + qrow + 32 + g * 8);
  bf16x8 aql0 = *(const bf16x8*)(qpl + qrow + g * 8);
  bf16x8 aql1 = *(const bf16x8*)(qpl + qrow + 32 + g * 8);

  float m[4], l[4];
  f32x4 o[4] = {};
#pragma unroll
  for (int r = 0; r < 4; ++r) { m[r] = -3.0e38f; l[r] = 0.f; }

  short* pl = Plds + w * 1024;
  const short* kphb = kph + (size_t)b * S_ * DH_;
  const short* kplb = kpl + (size_t)b * S_ * DH_;
  const short* vtb = vt + (size_t)b * S_;

  auto load_kh = [&](KHt& d, int kv) {
#pragma unroll
    for (int nt = 0; nt < 4; ++nt) {
      const size_t koff = (size_t)(kv + nt * 16 + c) * DH_ + g * 8;
      d.h[nt * 2]     = *(const bf16x8*)(kphb + koff);
      d.h[nt * 2 + 1] = *(const bf16x8*)(kphb + koff + 32);
    }
  };

  auto process = [&](const KHt& K, int kv) {
    // ---- scores: split QK^T (hi*hi, lo*hi, hi*lo) ----
    f32x4 s[4];
#pragma unroll
    for (int nt = 0; nt < 4; ++nt) {
      const size_t koff = (size_t)(kv + nt * 16 + c) * DH_ + g * 8;
      bf16x8 kl0 = *(const bf16x8*)(kplb + koff);
      bf16x8 kl1 = *(const bf16x8*)(kplb + koff + 32);
      f32x4 z = {};
      z = __builtin_amdgcn_mfma_f32_16x16x32_bf16(aqh0, K.h[nt * 2], z, 0, 0, 0);
      z = __builtin_amdgcn_mfma_f32_16x16x32_bf16(aqh1, K.h[nt * 2 + 1], z, 0, 0, 0);
      z = __builtin_amdgcn_mfma_f32_16x16x32_bf16(aql0, K.h[nt * 2], z, 0, 0, 0);
      z = __builtin_amdgcn_mfma_f32_16x16x32_bf16(aql1, K.h[nt * 2 + 1], z, 0, 0, 0);
      z = __builtin_amdgcn_mfma_f32_16x16x32_bf16(aqh0, kl0, z, 0, 0, 0);
      s[nt] = __builtin_amdgcn_mfma_f32_16x16x32_bf16(aqh1, kl1, z, 0, 0, 0);
    }
    // ---- online softmax ----
    float mx[4], rs[4], sc[4];
#pragma unroll
    for (int r = 0; r < 4; ++r)
      mx[r] = fmaxf(fmaxf(s[0][r], s[1][r]), fmaxf(s[2][r], s[3][r]));
#pragma unroll
    for (int off = 1; off < 16; off <<= 1)
#pragma unroll
      for (int r = 0; r < 4; ++r) mx[r] = fmaxf(mx[r], __shfl_xor(mx[r], off));
#pragma unroll
    for (int r = 0; r < 4; ++r) {
      float mn = fmaxf(m[r], mx[r]);
      sc[r] = __expf(m[r] - mn);
      m[r] = mn;
    }
#pragma unroll
    for (int nt = 0; nt < 4; ++nt)
#pragma unroll
      for (int r = 0; r < 4; ++r) s[nt][r] = __expf(s[nt][r] - m[r]);
#pragma unroll
    for (int r = 0; r < 4; ++r) rs[r] = (s[0][r] + s[1][r]) + (s[2][r] + s[3][r]);
#pragma unroll
    for (int off = 1; off < 16; off <<= 1)
#pragma unroll
      for (int r = 0; r < 4; ++r) rs[r] += __shfl_xor(rs[r], off);
#pragma unroll
    for (int r = 0; r < 4; ++r) l[r] = l[r] * sc[r] + rs[r];
#pragma unroll
    for (int f = 0; f < 4; ++f)
#pragma unroll
      for (int r = 0; r < 4; ++r) o[f][r] *= sc[r];
    // ---- P -> LDS (XOR-swizzled; same-wave only, compiler-ordered, HW in-order DS) ----
#pragma unroll
    for (int nt = 0; nt < 4; ++nt)
#pragma unroll
      for (int r = 0; r < 4; ++r) {
        int row = g * 4 + r, col = nt * 16 + c;
        int off2 = ((row << 7) + (col << 1)) ^ ((row & 7) << 4);
        *(short*)((char*)pl + off2) = f2bf(s[nt][r]);
      }
    bf16x8 pa[2];
#pragma unroll
    for (int kk = 0; kk < 2; ++kk) {
      int off2 = (c << 7) + ((((kk * 4 + g) ^ (c & 7))) << 4);
      pa[kk] = *(const bf16x8*)((const char*)pl + off2);
    }
    // ---- O += P V ----
#pragma unroll
    for (int f = 0; f < 4; ++f) {
      const short* vr = vtb + (size_t)(f * 16 + c) * MTOT + kv + g * 8;
      bf16x8 v0 = *(const bf16x8*)(vr);
      bf16x8 v1 = *(const bf16x8*)(vr + 32);
      o[f] = __builtin_amdgcn_mfma_f32_16x16x32_bf16(pa[0], v0, o[f], 0, 0, 0);
      o[f] = __builtin_amdgcn_mfma_f32_16x16x32_bf16(pa[1], v1, o[f], 0, 0, 0);
    }
  };

  // software pipeline: unroll-by-2, static double buffers (rule 20)
  KHt ka, kb;
  load_kh(ka, 0);
  for (int kv = 0; kv < S_; kv += 128) {
    load_kh(kb, kv + 64);
    process(ka, kv);
    if (kv + 128 < S_) load_kh(ka, kv + 128);
    process(kb, kv + 64);
  }

  // ---- epilogue: O / l -> ao split hi/lo at [token][h*64+dh] ----
  float inv[4];
#pragma unroll
  for (int r = 0; r < 4; ++r) inv[r] = 1.0f / l[r];
#pragma unroll
  for (int f = 0; f < 4; ++f)
#pragma unroll
    for (int r = 0; r < 4; ++r) {
      int row = b * S_ + q0 + g * 4 + r;
      int col = h * DH_ + f * 16 + c;
      bfpair pr = split2(o[f][r] * inv[r]);
      aoh[(size_t)row * D_ + col] = pr.hi;
      aol[(size_t)row * D_ + col] = pr.lo;
    }
}

// ---------------- launch ----------------
extern "C" void kernel_launch(void* const* d_in, const int* in_sizes, int n_in,
                              void* d_out, int out_size, void* d_ws, size_t ws_size,
                              hipStream_t stream) {
  const float* q  = (const float*)d_in[0];
  const float* k  = (const float*)d_in[1];
  const float* v  = (const float*)d_in[2];
  const float* wq = (const float*)d_in[3];
  const float* wk = (const float*)d_in[4];
  const float* wv = (const float*)d_in[5];
  const float* wo = (const float*)d_in[6];

  short* p = (short*)d_ws;
  short* qhi = p; p += 4194304;   // dead after Q-proj -> aoh
  short* qlo = p; p += 4194304;   // dead after Q-proj -> aol
  short* khi = p; p += 4194304;
  short* klo = p; p += 4194304;
  short* vb  = p; p += 4194304;
  short* wqh = p; p += 1048576;
  short* wql = p; p += 1048576;
  short* wkh = p; p += 65536;
  short* wkl = p; p += 65536;
  short* wvb = p; p += 65536;
  short* woh = p; p += 1048576;
  short* wol = p; p += 1048576;
  short* qph = p; p += 4194304;
  short* qpl = p; p += 4194304;
  short* kph = p; p += 262144;
  short* kpl = p; p += 262144;
  short* vt  = p; p += 262144;
  short* aoh = qhi;               // alias (stream-ordered reuse)
  short* aol = qlo;

  cvt_split<<<dim3(2048), dim3(256), 0, stream>>>(q, k, v, wq, wk, wv, wo,
      qhi, qlo, khi, klo, vb, wqh, wql, wkh, wkl, wvb, woh, wol);
  gemm3<3, 0><<<dim3(64, 16), dim3(256), 0, stream>>>(qhi, qlo, wqh, wql, qph, qpl,
      nullptr, 1024, 1024, 1024, 1024, 0.125f);
  gemm3<3, 0><<<dim3(64, 1), dim3(256), 0, stream>>>(khi, klo, wkh, wkl, kph, kpl,
      nullptr, 1024, 1024, 1024, 64, 1.0f);
  gemm3<1, 1><<<dim3(64, 1), dim3(256), 0, stream>>>(vb, nullptr, wvb, nullptr, vt,
      nullptr, nullptr, 1024, 1024, 1024, 4096, 1.0f);
  mqa_attn<<<dim3(32, 16, 2), dim3(256), 0, stream>>>(qph, qpl, kph, kpl, vt, aoh, aol);
  gemm3<3, 3><<<dim3(64, 16), dim3(256), 0, stream>>>(aoh, aol, woh, wol, nullptr,
      nullptr, (float*)d_out, 1024, 1024, 1024, 1024, 1.0f);
}

// Round 10
// 284.896 us; speedup vs baseline: 1.8258x; 1.8258x over previous
//
#include <hip/hip_runtime.h>
#include <hip/hip_bf16.h>
#include <stdint.h>

// MQA: B=2, S=2048, D=1024, H=16, DH=64. Inputs f32, OUTPUT f32.
// r10: attention rebuilt on the swapped-operand 32x32x16 structure (guide §B/T12):
//   scores = mfma(A=K, B=Q)  -> lane owns one q-row -> in-register softmax
//   P -> bf16 via v_cvt_pk_bf16_f32 + permlane32_swap (no LDS, no shuffle-reduce)
//   O^T += mfma(A=V^T, B=P^T) -> per-lane q ownership preserved
// exp2-domain softmax (log2e folded into Q-proj alpha; verified green in r7).
// Projections/out-proj: unchanged verified split-bf16 MFMA GEMMs (r6).

#define B_   2
#define S_   2048
#define D_   1024
#define H_   16
#define DH_  64
#define MTOT (B_ * S_)  // 4096

typedef short bf16x8 __attribute__((ext_vector_type(8)));
typedef float f32x4 __attribute__((ext_vector_type(4)));
typedef float f32x16 __attribute__((ext_vector_type(16)));
typedef short short4v __attribute__((ext_vector_type(4)));
typedef unsigned uint4v __attribute__((ext_vector_type(4)));

__device__ __forceinline__ short f2bf(float f) {  // RNE f32->bf16
  unsigned u = __float_as_uint(f);
  u += 0x7FFF + ((u >> 16) & 1);
  return (short)(u >> 16);
}
__device__ __forceinline__ float bf2f(short h) {
  return __uint_as_float(((unsigned)(unsigned short)h) << 16);
}
struct bfpair { short hi, lo; };
__device__ __forceinline__ bfpair split2(float x) {
  bfpair p;
  p.hi = f2bf(x);
  p.lo = f2bf(x - bf2f(p.hi));
  return p;
}
__device__ __forceinline__ unsigned cvtpk(float lo, float hi) {  // D.lo=cvt(lo), D.hi=cvt(hi)
  unsigned r;
  asm("v_cvt_pk_bf16_f32 %0, %1, %2" : "=v"(r) : "v"(lo), "v"(hi));
  return r;
}

__device__ __forceinline__ void glds16(const void* g, void* l) {
  __builtin_amdgcn_global_load_lds((const __attribute__((address_space(1))) void*)g,
                                   (__attribute__((address_space(3))) void*)l, 16, 0, 0);
}

// ---------------- f32 -> bf16 convert, hi/lo split where needed ----------------
__global__ __launch_bounds__(256) void cvt_split(
    const float* __restrict__ q, const float* __restrict__ k, const float* __restrict__ v,
    const float* __restrict__ wq, const float* __restrict__ wk, const float* __restrict__ wv,
    const float* __restrict__ wo,
    short* qhi, short* qlo, short* khi, short* klo, short* vb,
    short* wqh, short* wql, short* wkh, short* wkl, short* wvb,
    short* woh, short* wol) {
  const int U0 = 1048576, U1 = 2097152, U2 = 3145728, U3 = 3407872,
            U4 = 3424256, U5 = 3440640, U6 = 3702784;
  for (int u = blockIdx.x * blockDim.x + threadIdx.x; u < U6; u += gridDim.x * blockDim.x) {
    const float* s; short* dh; short* dl; int r;
    if (u < U0)      { s = q;  dh = qhi; dl = qlo; r = u; }
    else if (u < U1) { s = k;  dh = khi; dl = klo; r = u - U0; }
    else if (u < U2) { s = v;  dh = vb;  dl = nullptr; r = u - U1; }
    else if (u < U3) { s = wq; dh = wqh; dl = wql; r = u - U2; }
    else if (u < U4) { s = wk; dh = wkh; dl = wkl; r = u - U3; }
    else if (u < U5) { s = wv; dh = wvb; dl = nullptr; r = u - U4; }
    else             { s = wo; dh = woh; dl = wol; r = u - U5; }
    float4 x = *(const float4*)(s + (size_t)r * 4);
    bfpair p0 = split2(x.x), p1 = split2(x.y), p2 = split2(x.z), p3 = split2(x.w);
    short4v yh, yl;
    yh.x = p0.hi; yh.y = p1.hi; yh.z = p2.hi; yh.w = p3.hi;
    yl.x = p0.lo; yl.y = p1.lo; yl.z = p2.lo; yl.w = p3.lo;
    *(short4v*)(dh + (size_t)r * 4) = yh;
    if (dl) *(short4v*)(dl + (size_t)r * 4) = yl;
  }
}

// ---------------- GEMM  C = (Ah+Al) * (Bh+Bl)^T, f32 acc (verified r6) ----------------
template <int NPROD, int MODE>
__global__ __launch_bounds__(256) void gemm3(
    const short* __restrict__ Ah, const short* __restrict__ Al,
    const short* __restrict__ Bh, const short* __restrict__ Bl,
    short* __restrict__ Ch, short* __restrict__ Cl, float* __restrict__ Cf,
    int K, int lda, int ldb, int ldc, float alpha) {
  __shared__ alignas(16) short Ash[4096], Asl[4096], Bsh[4096], Bsl[4096];
  const int tid = threadIdx.x;
  const int lane = tid & 63, w = tid >> 6;
  const int c = lane & 15, g = lane >> 4;
  const int wm = w >> 1, wn = w & 1;
  const int bm = blockIdx.x * 64, bn = blockIdx.y * 64;
  const int sr = lane >> 3;
  const int scs = ((lane & 7) ^ sr) * 8;

  f32x4 acc[2][2] = {};
  for (int k0 = 0; k0 < K; k0 += 64) {
    glds16(Ah + (size_t)(bm + w * 8 + sr) * lda + k0 + scs,      Ash + w * 512);
    glds16(Ah + (size_t)(bm + 32 + w * 8 + sr) * lda + k0 + scs, Ash + 2048 + w * 512);
    glds16(Bh + (size_t)(bn + w * 8 + sr) * ldb + k0 + scs,      Bsh + w * 512);
    glds16(Bh + (size_t)(bn + 32 + w * 8 + sr) * ldb + k0 + scs, Bsh + 2048 + w * 512);
    if constexpr (NPROD == 3) {
      glds16(Al + (size_t)(bm + w * 8 + sr) * lda + k0 + scs,      Asl + w * 512);
      glds16(Al + (size_t)(bm + 32 + w * 8 + sr) * lda + k0 + scs, Asl + 2048 + w * 512);
      glds16(Bl + (size_t)(bn + w * 8 + sr) * ldb + k0 + scs,      Bsl + w * 512);
      glds16(Bl + (size_t)(bn + 32 + w * 8 + sr) * ldb + k0 + scs, Bsl + 2048 + w * 512);
    }
    __syncthreads();
#pragma unroll
    for (int kk = 0; kk < 2; ++kk) {
      bf16x8 ah[2], bh[2], al[2], bl[2];
#pragma unroll
      for (int mt = 0; mt < 2; ++mt) {
        int row = wm * 32 + mt * 16 + c;
        int so = row * 64 + (((kk * 4 + g) ^ (row & 7)) * 8);
        ah[mt] = *(const bf16x8*)(Ash + so);
        if constexpr (NPROD == 3) al[mt] = *(const bf16x8*)(Asl + so);
      }
#pragma unroll
      for (int nt = 0; nt < 2; ++nt) {
        int row = wn * 32 + nt * 16 + c;
        int so = row * 64 + (((kk * 4 + g) ^ (row & 7)) * 8);
        bh[nt] = *(const bf16x8*)(Bsh + so);
        if constexpr (NPROD == 3) bl[nt] = *(const bf16x8*)(Bsl + so);
      }
#pragma unroll
      for (int mt = 0; mt < 2; ++mt)
#pragma unroll
        for (int nt = 0; nt < 2; ++nt) {
          acc[mt][nt] = __builtin_amdgcn_mfma_f32_16x16x32_bf16(ah[mt], bh[nt], acc[mt][nt], 0, 0, 0);
          if constexpr (NPROD == 3) {
            acc[mt][nt] = __builtin_amdgcn_mfma_f32_16x16x32_bf16(ah[mt], bl[nt], acc[mt][nt], 0, 0, 0);
            acc[mt][nt] = __builtin_amdgcn_mfma_f32_16x16x32_bf16(al[mt], bh[nt], acc[mt][nt], 0, 0, 0);
          }
        }
    }
    __syncthreads();
  }
#pragma unroll
  for (int mt = 0; mt < 2; ++mt) {
#pragma unroll
    for (int nt = 0; nt < 2; ++nt) {
      if constexpr (MODE == 0) {
#pragma unroll
        for (int r = 0; r < 4; ++r) {
          int m = bm + wm * 32 + mt * 16 + g * 4 + r;
          int n = bn + wn * 32 + nt * 16 + c;
          bfpair pr = split2(acc[mt][nt][r] * alpha);
          Ch[(size_t)m * ldc + n] = pr.hi;
          Cl[(size_t)m * ldc + n] = pr.lo;
        }
      } else if constexpr (MODE == 1) {
        int n = bn + wn * 32 + nt * 16 + c;
        int m = bm + wm * 32 + mt * 16 + g * 4;
        short4v y;
        y.x = f2bf(acc[mt][nt][0] * alpha);
        y.y = f2bf(acc[mt][nt][1] * alpha);
        y.z = f2bf(acc[mt][nt][2] * alpha);
        y.w = f2bf(acc[mt][nt][3] * alpha);
        *(short4v*)(Ch + (size_t)n * ldc + m) = y;
      } else {
#pragma unroll
        for (int r = 0; r < 4; ++r) {
          int m = bm + wm * 32 + mt * 16 + g * 4 + r;
          int n = bn + wn * 32 + nt * 16 + c;
          Cf[(size_t)m * ldc + n] = acc[mt][nt][r] * alpha;
        }
      }
    }
  }
}

// ---------------- flash MQA attention v4: swapped-operand, register-only ----------------
// grid (S/128, H, B), 256 thr = 4 waves; wave w owns 32 q-rows (q0 = bx*128 + w*32).
// Lane l: j = l&31 owns q-row q0+j fully; b5 = l>>5.
// Scores: D[kv][q] = mfma32x32x16(A=K, B=Q) chained over 4 dh-chunks, split x3.
// Softmax per lane: in-register tree + one __shfl_xor(32) exchange. exp2 domain.
// P^T fragment assembled in-register via cvt_pk + permlane32_swap (T12).
// O^T accum: D[dh][q] = mfma(A=V^T, B=P^T), 2 dh-halves x 2 kv-chunks.
__global__ __launch_bounds__(256) void mqa_attn(
    const short* __restrict__ qph, const short* __restrict__ qpl,
    const short* __restrict__ kph, const short* __restrict__ kpl,
    const short* __restrict__ vt, short* __restrict__ aoh, short* __restrict__ aol) {
  const int tid = threadIdx.x;
  const int lane = tid & 63, w = tid >> 6;
  const int j = lane & 31, b5 = lane >> 5;
  const int qt = blockIdx.x, h = blockIdx.y, b = blockIdx.z;
  const int q0 = qt * 128 + w * 32;

  // Q fragments: B-operand, col=j (q-row q0+j), k = b5*8 + i within each 16-dh chunk
  const size_t qbase = (size_t)(b * S_ + q0 + j) * D_ + h * DH_ + b5 * 8;
  bf16x8 qh[4], ql[4];
#pragma unroll
  for (int m = 0; m < 4; ++m) {
    qh[m] = *(const bf16x8*)(qph + qbase + m * 16);
    ql[m] = *(const bf16x8*)(qpl + qbase + m * 16);
  }

  float mrow = -1.0e30f, lrow = 0.f;
  f32x16 o0 = {}, o1 = {};

  const short* kphb = kph + (size_t)b * S_ * DH_;
  const short* kplb = kpl + (size_t)b * S_ * DH_;
  const short* vtb = vt + (size_t)b * S_;

  for (int kv0 = 0; kv0 < S_; kv0 += 32) {
    // ---- K fragments: A-operand, row=kv0+j, k = b5*8+i per 16-dh chunk ----
    const size_t kbase = (size_t)(kv0 + j) * DH_ + b5 * 8;
    bf16x8 kh[4], kl[4];
#pragma unroll
    for (int m = 0; m < 4; ++m) {
      kh[m] = *(const bf16x8*)(kphb + kbase + m * 16);
      kl[m] = *(const bf16x8*)(kplb + kbase + m * 16);
    }
    // ---- scores: 3 independent 4-chains (hh, lh, hl), summed ----
    f32x16 sa = {}, sb = {}, sc2 = {};
#pragma unroll
    for (int m = 0; m < 4; ++m) {
      sa  = __builtin_amdgcn_mfma_f32_32x32x16_bf16(kh[m], qh[m], sa, 0, 0, 0);
      sb  = __builtin_amdgcn_mfma_f32_32x32x16_bf16(kl[m], qh[m], sb, 0, 0, 0);
      sc2 = __builtin_amdgcn_mfma_f32_32x32x16_bf16(kh[m], ql[m], sc2, 0, 0, 0);
    }
    f32x16 s = (sa + sb) + sc2;  // log2-domain scores; lane holds q-col j, 16 kv rows
    // ---- in-register online softmax (q-row j local to lanes j and j+32) ----
    float mx = s[0];
#pragma unroll
    for (int r = 1; r < 16; ++r) mx = fmaxf(mx, s[r]);
    mx = fmaxf(mx, __shfl_xor(mx, 32));
    float mn = fmaxf(mrow, mx);
    float scale = exp2f(mrow - mn);
    mrow = mn;
    float p[16];
#pragma unroll
    for (int r = 0; r < 16; ++r) p[r] = exp2f(s[r] - mn);
    float rs = (((p[0] + p[1]) + (p[2] + p[3])) + ((p[4] + p[5]) + (p[6] + p[7]))) +
               (((p[8] + p[9]) + (p[10] + p[11])) + ((p[12] + p[13]) + (p[14] + p[15])));
    rs += __shfl_xor(rs, 32);
    lrow = lrow * scale + rs;
    o0 *= scale;
    o1 *= scale;
    // ---- P^T fragments via cvt_pk + permlane32_swap (one swap fills two words) ----
    auto r0 = __builtin_amdgcn_permlane32_swap(cvtpk(p[0], p[1]),   cvtpk(p[4], p[5]),   false, false);
    auto r1 = __builtin_amdgcn_permlane32_swap(cvtpk(p[2], p[3]),   cvtpk(p[6], p[7]),   false, false);
    auto r2 = __builtin_amdgcn_permlane32_swap(cvtpk(p[8], p[9]),   cvtpk(p[12], p[13]), false, false);
    auto r3 = __builtin_amdgcn_permlane32_swap(cvtpk(p[10], p[11]), cvtpk(p[14], p[15]), false, false);
    union { uint4v u; bf16x8 v; } pa0, pa1;
    pa0.u = (uint4v){r0[0], r1[0], r0[1], r1[1]};  // kv kc*? : [w0 w1 w2 w3] = kv 0..15 (per b5 half)
    pa1.u = (uint4v){r2[0], r3[0], r2[1], r3[1]};  // kv 16..31
    // ---- O^T += V^T x P^T : A row = dh (dhh*32 + j), k = kv = kc*16 + b5*8 + i ----
    const short* vr0 = vtb + (size_t)j * MTOT + kv0 + b5 * 8;          // dh 0..31
    const short* vr1 = vtb + (size_t)(32 + j) * MTOT + kv0 + b5 * 8;   // dh 32..63
    bf16x8 va00 = *(const bf16x8*)(vr0);
    bf16x8 va01 = *(const bf16x8*)(vr0 + 16);
    bf16x8 va10 = *(const bf16x8*)(vr1);
    bf16x8 va11 = *(const bf16x8*)(vr1 + 16);
    o0 = __builtin_amdgcn_mfma_f32_32x32x16_bf16(va00, pa0.v, o0, 0, 0, 0);
    o0 = __builtin_amdgcn_mfma_f32_32x32x16_bf16(va01, pa1.v, o0, 0, 0, 0);
    o1 = __builtin_amdgcn_mfma_f32_32x32x16_bf16(va10, pa0.v, o1, 0, 0, 0);
    o1 = __builtin_amdgcn_mfma_f32_32x32x16_bf16(va11, pa1.v, o1, 0, 0, 0);
  }
  // ---- epilogue: O^T/l -> ao split hi/lo; lane j owns q-row q0+j ----
  float inv = 1.0f / lrow;
  const size_t obase = (size_t)(b * S_ + q0 + j) * D_ + h * DH_;
#pragma unroll
  for (int r = 0; r < 16; ++r) {
    int dh0 = (r & 3) + 8 * (r >> 2) + 4 * b5;        // rows of o0
    bfpair pr0 = split2(o0[r] * inv);
    aoh[obase + dh0] = pr0.hi;
    aol[obase + dh0] = pr0.lo;
    bfpair pr1 = split2(o1[r] * inv);
    aoh[obase + 32 + dh0] = pr1.hi;
    aol[obase + 32 + dh0] = pr1.lo;
  }
}

// ---------------- launch ----------------
extern "C" void kernel_launch(void* const* d_in, const int* in_sizes, int n_in,
                              void* d_out, int out_size, void* d_ws, size_t ws_size,
                              hipStream_t stream) {
  const float* q  = (const float*)d_in[0];
  const float* k  = (const float*)d_in[1];
  const float* v  = (const float*)d_in[2];
  const float* wq = (const float*)d_in[3];
  const float* wk = (const float*)d_in[4];
  const float* wv = (const float*)d_in[5];
  const float* wo = (const float*)d_in[6];

  short* p = (short*)d_ws;
  short* qhi = p; p += 4194304;   // dead after Q-proj -> aoh
  short* qlo = p; p += 4194304;   // dead after Q-proj -> aol
  short* khi = p; p += 4194304;
  short* klo = p; p += 4194304;
  short* vb  = p; p += 4194304;
  short* wqh = p; p += 1048576;
  short* wql = p; p += 1048576;
  short* wkh = p; p += 65536;
  short* wkl = p; p += 65536;
  short* wvb = p; p += 65536;
  short* woh = p; p += 1048576;
  short* wol = p; p += 1048576;
  short* qph = p; p += 4194304;
  short* qpl = p; p += 4194304;
  short* kph = p; p += 262144;
  short* kpl = p; p += 262144;
  short* vt  = p; p += 262144;
  short* aoh = qhi;               // alias (stream-ordered reuse)
  short* aol = qlo;

  cvt_split<<<dim3(2048), dim3(256), 0, stream>>>(q, k, v, wq, wk, wv, wo,
      qhi, qlo, khi, klo, vb, wqh, wql, wkh, wkl, wvb, woh, wol);
  // qp = q @ wq^T * (0.125 * log2e)  -> exp2-domain scores (r7-verified)
  gemm3<3, 0><<<dim3(64, 16), dim3(256), 0, stream>>>(qhi, qlo, wqh, wql, qph, qpl,
      nullptr, 1024, 1024, 1024, 1024, 0.125f * 1.44269504f);
  gemm3<3, 0><<<dim3(64, 1), dim3(256), 0, stream>>>(khi, klo, wkh, wkl, kph, kpl,
      nullptr, 1024, 1024, 1024, 64, 1.0f);
  gemm3<1, 1><<<dim3(64, 1), dim3(256), 0, stream>>>(vb, nullptr, wvb, nullptr, vt,
      nullptr, nullptr, 1024, 1024, 1024, 4096, 1.0f);
  mqa_attn<<<dim3(S_ / 128, 16, 2), dim3(256), 0, stream>>>(qph, qpl, kph, kpl, vt, aoh, aol);
  gemm3<3, 3><<<dim3(64, 16), dim3(256), 0, stream>>>(aoh, aol, woh, wol, nullptr,
      nullptr, (float*)d_out, 1024, 1024, 1024, 1024, 1.0f);
}